// Round 8
// baseline (232.230 us; speedup 1.0000x reference)
//
#include <hip/hip_runtime.h>
#include <hip/hip_bf16.h>

typedef __bf16 bf16_t;
typedef __bf16 bf16x8 __attribute__((ext_vector_type(8)));
typedef float f32x4 __attribute__((ext_vector_type(4)));
typedef unsigned int u32;

#define NB 16
#define HW 56
#define DIM 192
#define N3 576
#define WS7 7
#define HEADS 6
#define HD 32
#define NTOK 49
#define MFMA(a, b, c) __builtin_amdgcn_mfma_f32_16x16x32_bf16(a, b, c, 0, 0, 0)

__device__ __forceinline__ void gld_lds16(const bf16_t* g, bf16_t* l) {
    __builtin_amdgcn_global_load_lds((const __attribute__((address_space(1))) u32*)g,
                                     (__attribute__((address_space(3))) u32*)l, 16, 0, 0);
}

// ---------------- prep: roll(-3,-3) + fp32->bf16 of x ----------------
__global__ __launch_bounds__(256) void prep_x_kernel(const float* __restrict__ x,
                                                     bf16_t* __restrict__ xb) {
    int idx = blockIdx.x * 256 + threadIdx.x;
    const int total = NB * HW * HW * (DIM / 8);
    if (idx >= total) return;
    int c8 = idx % (DIM / 8);
    int p  = idx / (DIM / 8);
    int xx = p % HW;
    int yy = (p / HW) % HW;
    int bb = p / (HW * HW);
    int ys = yy + 3; if (ys >= HW) ys -= HW;
    int xs = xx + 3; if (xs >= HW) xs -= HW;
    const float* src = x + ((size_t)(bb * HW + ys) * HW + xs) * DIM + c8 * 8;
    float4 a0 = *reinterpret_cast<const float4*>(src);
    float4 a1 = *reinterpret_cast<const float4*>(src + 4);
    bf16x8 o;
    o[0] = (bf16_t)a0.x; o[1] = (bf16_t)a0.y; o[2] = (bf16_t)a0.z; o[3] = (bf16_t)a0.w;
    o[4] = (bf16_t)a1.x; o[5] = (bf16_t)a1.y; o[6] = (bf16_t)a1.z; o[7] = (bf16_t)a1.w;
    *reinterpret_cast<bf16x8*>(xb + (size_t)idx * 8) = o;
}

// ---------------- prep: transpose+cast weights to [n][k] bf16 ----------------
__global__ __launch_bounds__(256) void prep_w_kernel(const float* __restrict__ wqkv,
                                                     const float* __restrict__ wout,
                                                     bf16_t* __restrict__ wqkvt,
                                                     bf16_t* __restrict__ woutt) {
    int idx = blockIdx.x * 256 + threadIdx.x;
    if (idx < N3 * DIM) {
        int k = idx % DIM, n = idx / DIM;
        wqkvt[idx] = (bf16_t)wqkv[(size_t)k * N3 + n];
    } else {
        int j = idx - N3 * DIM;
        if (j < DIM * DIM) {
            int k = j % DIM, n = j / DIM;
            woutt[j] = (bf16_t)wout[(size_t)k * DIM + n];
        }
    }
}

// ---------------- prep: bias+shift-mask tables  tbl[4][64][64] f32 ----------------
__global__ __launch_bounds__(256) void prep_tbl_kernel(const float* __restrict__ pe,
                                                       float* __restrict__ tbl) {
    int idx = blockIdx.x * 256 + threadIdx.x;     // 4*64*64 = 16384
    if (idx >= 4 * 64 * 64) return;
    int v = idx >> 12, rem = idx & 4095, ti = rem >> 6, tj = rem & 63;
    float val = -1e9f;
    if (ti < NTOK && tj < NTOK) {
        int yi = ti / 7, xi = ti % 7, yj = tj / 7, xj = tj % 7;
        val = pe[(yj - yi + 6) * 13 + (xj - xi + 6)];
        bool mr = (v & 2) && ((yi >= 4) != (yj >= 4));
        bool mc = (v & 1) && ((xi >= 4) != (xj >= 4));
        if (mr || mc) val = -1e9f;
    }
    tbl[idx] = val;
}

// ---------------- K1: fused QKV-projection + windowed attention ----------------
// block = (head, window, batch), 4 waves; wave mt owns tokens mt*16..+15.
// Phase 1: q,k,v = xb_tile @ wqkvt_head (36 MFMAs/wave, B-frags from L2).
// Phase 2: Q,K (token-major) and V^T staged in LDS; one barrier.
// Phase 3: QK^T (K=32, 4 MFMAs) + table softmax + PV (4 MFMAs) -> att.
__global__ __launch_bounds__(256, 4) void fused_attn_kernel(const bf16_t* __restrict__ xb,
                                                            const bf16_t* __restrict__ wt,
                                                            const float* __restrict__ tbl,
                                                            bf16_t* __restrict__ att) {
    const int h = blockIdx.x, win = blockIdx.y, bb = blockIdx.z;
    const int wh = win >> 3, ww = win & 7;
    const int mt = threadIdx.x >> 6;
    const int lane = threadIdx.x & 63;
    const int lo = lane & 15, hi = lane >> 4;

    __shared__ alignas(16) bf16_t Qs[64 * 40];   // [tok][ch], stride 40 (80 B)
    __shared__ alignas(16) bf16_t Ks[64 * 40];
    __shared__ alignas(16) bf16_t VTs[32 * 72];  // [ch][tok], stride 72 (144 B)
    __shared__ alignas(16) bf16_t P[64 * 72];

    // ---- phase 1: QKV projection for own 16 tokens ----
    bf16x8 a[6];
    {
        int t = mt * 16 + lo;
        if (t >= NTOK) t = 0;                    // padded rows alias token 0
        int y = wh * WS7 + t / 7, xcol = ww * WS7 + t % 7;
        const bf16_t* ar = xb + ((size_t)(bb * HW + y) * HW + xcol) * DIM + hi * 8;
#pragma unroll
        for (int ks = 0; ks < 6; ks++)
            a[ks] = *reinterpret_cast<const bf16x8*>(ar + ks * 32);
    }

    f32x4 acc6[3][2];
#pragma unroll
    for (int s = 0; s < 3; s++)
#pragma unroll
        for (int nt = 0; nt < 2; nt++) acc6[s][nt] = (f32x4){0.f, 0.f, 0.f, 0.f};

#pragma unroll
    for (int s = 0; s < 3; s++)
#pragma unroll
        for (int nt = 0; nt < 2; nt++) {
            const bf16_t* bp = wt + (size_t)(s * DIM + h * HD + nt * 16 + lo) * DIM + hi * 8;
#pragma unroll
            for (int ks = 0; ks < 6; ks++) {
                bf16x8 bf = *reinterpret_cast<const bf16x8*>(bp + ks * 32);
                acc6[s][nt] = MFMA(a[ks], bf, acc6[s][nt]);
            }
        }

    // ---- phase 2: stage Q (prescaled), K token-major; V transposed ----
    const float qs = 0.17677669529663687f;       // 1/sqrt(32)
#pragma unroll
    for (int nt = 0; nt < 2; nt++)
#pragma unroll
        for (int r = 0; r < 4; r++) {
            int tok = mt * 16 + hi * 4 + r;
            Qs[tok * 40 + nt * 16 + lo] = (bf16_t)(acc6[0][nt][r] * qs);
            Ks[tok * 40 + nt * 16 + lo] = (bf16_t)acc6[1][nt][r];
            VTs[(nt * 16 + lo) * 72 + tok] = (bf16_t)acc6[2][nt][r];
        }
    __syncthreads();

    // ---- phase 3a: S = Q K^T  (one MFMA per 16x16 tile, K=32) ----
    const f32x4 zero4 = {0.f, 0.f, 0.f, 0.f};
    bf16x8 qa = *reinterpret_cast<const bf16x8*>(&Qs[(mt * 16 + lo) * 40 + hi * 8]);
    f32x4 s4[4];
#pragma unroll
    for (int ct = 0; ct < 4; ct++) {
        bf16x8 kb = *reinterpret_cast<const bf16x8*>(&Ks[(ct * 16 + lo) * 40 + hi * 8]);
        s4[ct] = MFMA(qa, kb, zero4);
    }

    // ---- phase 3b: softmax with bias+mask table ----
    const int variant = ((wh == 7) ? 2 : 0) | ((ww == 7) ? 1 : 0);
    const float* tbase = tbl + ((size_t)variant << 12);
    float rinv[4];
#pragma unroll
    for (int r = 0; r < 4; r++) {
        int ti = mt * 16 + hi * 4 + r;
        const float* trow = tbase + ti * 64 + lo;
        float vals[4];
        float mx = -3e38f;
#pragma unroll
        for (int ct = 0; ct < 4; ct++) {
            float v = s4[ct][r] + trow[ct * 16];
            vals[ct] = v;
            mx = fmaxf(mx, v);
        }
#pragma unroll
        for (int off = 1; off < 16; off <<= 1) mx = fmaxf(mx, __shfl_xor(mx, off));
        float sum = 0.f;
#pragma unroll
        for (int ct = 0; ct < 4; ct++) {
            float p = __expf(vals[ct] - mx);
            sum += p;
            P[ti * 72 + ct * 16 + lo] = (bf16_t)p;
        }
#pragma unroll
        for (int off = 1; off < 16; off <<= 1) sum += __shfl_xor(sum, off);
        rinv[r] = 1.f / sum;
    }

    // ---- phase 3c: O = P V  (P rows wave-local; VTs ready since barrier) ----
    f32x4 o[2] = {zero4, zero4};
#pragma unroll
    for (int ks = 0; ks < 2; ks++) {
        bf16x8 pa = *reinterpret_cast<const bf16x8*>(&P[(mt * 16 + lo) * 72 + ks * 32 + hi * 8]);
#pragma unroll
        for (int c2 = 0; c2 < 2; c2++) {
            bf16x8 vb = *reinterpret_cast<const bf16x8*>(&VTs[(c2 * 16 + lo) * 72 + ks * 32 + hi * 8]);
            o[c2] = MFMA(pa, vb, o[c2]);
        }
    }

#pragma unroll
    for (int r = 0; r < 4; r++) {
        int ti = mt * 16 + hi * 4 + r;
        if (ti < NTOK) {
            int y = wh * WS7 + ti / 7, xcol = ww * WS7 + ti % 7;
            size_t aoff = ((size_t)(bb * HW + y) * HW + xcol) * DIM + h * HD;
#pragma unroll
            for (int c2 = 0; c2 < 2; c2++)
                att[aoff + c2 * 16 + lo] = (bf16_t)(o[c2][r] * rinv[r]);
        }
    }
}

// ---------------- K3: out GEMM + bias + roll(+3,+3) ----------------
__global__ __launch_bounds__(256) void out_gemm2(const bf16_t* __restrict__ att,
                                                 const bf16_t* __restrict__ wt,
                                                 const float* __restrict__ bias,
                                                 float* __restrict__ out) {
    __shared__ alignas(16) bf16_t bsh[64 * DIM];
    const int mblk = blockIdx.x, nblk = blockIdx.y;
    const int wave = threadIdx.x >> 6, lane = threadIdx.x & 63;
    const int lo = lane & 15, hi = lane >> 4;

    const bf16_t* bt = wt + (size_t)nblk * 64 * DIM;
#pragma unroll
    for (int i = 0; i < 6; i++) {
        int s = wave * 384 + i * 64 + lane;
        int g = s ^ ((s / 24) & 7);
        gld_lds16(bt + g * 8, bsh + (wave * 384 + i * 64) * 8);
    }

    bf16x8 a[2][6];
    const bf16_t* ab = att + ((size_t)mblk * 128 + wave * 32 + lo) * DIM + hi * 8;
#pragma unroll
    for (int mt = 0; mt < 2; mt++)
#pragma unroll
        for (int ks = 0; ks < 6; ks++)
            a[mt][ks] = *reinterpret_cast<const bf16x8*>(ab + mt * 16 * DIM + ks * 32);

    f32x4 acc[2][4];
#pragma unroll
    for (int mt = 0; mt < 2; mt++)
#pragma unroll
        for (int ct = 0; ct < 4; ct++) acc[mt][ct] = (f32x4){0.f, 0.f, 0.f, 0.f};

    __syncthreads();

#pragma unroll
    for (int ks = 0; ks < 6; ks++)
#pragma unroll
        for (int ct = 0; ct < 4; ct++) {
            int r = ct * 16 + lo;
            int off = (ks * 64 + hi * 16) ^ ((r & 7) << 4);
            bf16x8 b = *reinterpret_cast<const bf16x8*>((const char*)bsh + r * 384 + off);
            acc[0][ct] = MFMA(a[0][ks], b, acc[0][ct]);
            acc[1][ct] = MFMA(a[1][ks], b, acc[1][ct]);
        }

    const int rb = mblk * 128 + wave * 32;
#pragma unroll
    for (int mt = 0; mt < 2; mt++)
#pragma unroll
        for (int r = 0; r < 4; r++) {
            int m = rb + mt * 16 + hi * 4 + r;
            int bb = m / (HW * HW);
            int rem = m - bb * HW * HW;
            int ya = rem / HW, xa = rem - ya * HW;
            int yo = ya + 3; if (yo >= HW) yo -= HW;
            int xo = xa + 3; if (xo >= HW) xo -= HW;
            size_t ob = ((size_t)(bb * HW + yo) * HW + xo) * DIM + nblk * 64;
#pragma unroll
            for (int ct = 0; ct < 4; ct++)
                out[ob + ct * 16 + lo] = acc[mt][ct][r] + bias[nblk * 64 + ct * 16 + lo];
        }
}

extern "C" void kernel_launch(void* const* d_in, const int* in_sizes, int n_in,
                              void* d_out, int out_size, void* d_ws, size_t ws_size,
                              hipStream_t stream) {
    const float* x    = (const float*)d_in[0];
    const float* wqkv = (const float*)d_in[1];
    const float* pe   = (const float*)d_in[2];
    const float* wout = (const float*)d_in[3];
    const float* bout = (const float*)d_in[4];
    float* out = (float*)d_out;

    char* ws = (char*)d_ws;
    const size_t XB_BYTES  = (size_t)NB * HW * HW * DIM * 2;   // 19,267,584
    const size_t ATT_BYTES = XB_BYTES;
    const size_t WQ_BYTES  = (size_t)N3 * DIM * 2;
    const size_t WO_BYTES  = (size_t)DIM * DIM * 2;
    bf16_t* xb    = (bf16_t*)ws;
    bf16_t* att   = (bf16_t*)(ws + XB_BYTES);
    bf16_t* wqkvt = (bf16_t*)(ws + XB_BYTES + ATT_BYTES);
    bf16_t* woutt = (bf16_t*)(ws + XB_BYTES + ATT_BYTES + WQ_BYTES);
    float*  tbl   = (float*)(ws + XB_BYTES + ATT_BYTES + WQ_BYTES + WO_BYTES);

    prep_x_kernel<<<(NB * HW * HW * (DIM / 8) + 255) / 256, 256, 0, stream>>>(x, xb);
    prep_w_kernel<<<(N3 * DIM + DIM * DIM + 255) / 256, 256, 0, stream>>>(wqkv, wout, wqkvt, woutt);
    prep_tbl_kernel<<<64, 256, 0, stream>>>(pe, tbl);
    fused_attn_kernel<<<dim3(HEADS, 64, NB), 256, 0, stream>>>(xb, wqkvt, tbl, att);
    out_gemm2<<<dim3(392, 3), 256, 0, stream>>>(att, woutt, bout, out);
}

// Round 9
// 154.365 us; speedup vs baseline: 1.5044x; 1.5044x over previous
//
#include <hip/hip_runtime.h>
#include <hip/hip_bf16.h>

typedef __bf16 bf16_t;
typedef __bf16 bf16x8 __attribute__((ext_vector_type(8)));
typedef float f32x4 __attribute__((ext_vector_type(4)));
typedef unsigned int u32;

#define NB 16
#define HW 56
#define DIM 192
#define N3 576
#define WS7 7
#define HEADS 6
#define HD 32
#define NTOK 49
#define MFMA(a, b, c) __builtin_amdgcn_mfma_f32_16x16x32_bf16(a, b, c, 0, 0, 0)

__device__ __forceinline__ void gld_lds16(const bf16_t* g, bf16_t* l) {
    __builtin_amdgcn_global_load_lds((const __attribute__((address_space(1))) u32*)g,
                                     (__attribute__((address_space(3))) u32*)l, 16, 0, 0);
}

// ---------------- prep: roll(-3,-3) + fp32->bf16 of x ----------------
__global__ __launch_bounds__(256) void prep_x_kernel(const float* __restrict__ x,
                                                     bf16_t* __restrict__ xb) {
    int idx = blockIdx.x * 256 + threadIdx.x;
    const int total = NB * HW * HW * (DIM / 8);
    if (idx >= total) return;
    int c8 = idx % (DIM / 8);
    int p  = idx / (DIM / 8);
    int xx = p % HW;
    int yy = (p / HW) % HW;
    int bb = p / (HW * HW);
    int ys = yy + 3; if (ys >= HW) ys -= HW;
    int xs = xx + 3; if (xs >= HW) xs -= HW;
    const float* src = x + ((size_t)(bb * HW + ys) * HW + xs) * DIM + c8 * 8;
    float4 a0 = *reinterpret_cast<const float4*>(src);
    float4 a1 = *reinterpret_cast<const float4*>(src + 4);
    bf16x8 o;
    o[0] = (bf16_t)a0.x; o[1] = (bf16_t)a0.y; o[2] = (bf16_t)a0.z; o[3] = (bf16_t)a0.w;
    o[4] = (bf16_t)a1.x; o[5] = (bf16_t)a1.y; o[6] = (bf16_t)a1.z; o[7] = (bf16_t)a1.w;
    *reinterpret_cast<bf16x8*>(xb + (size_t)idx * 8) = o;
}

// ---------------- prep: transpose+cast weights to [n][k] bf16 ----------------
__global__ __launch_bounds__(256) void prep_w_kernel(const float* __restrict__ wqkv,
                                                     const float* __restrict__ wout,
                                                     bf16_t* __restrict__ wqkvt,
                                                     bf16_t* __restrict__ woutt) {
    int idx = blockIdx.x * 256 + threadIdx.x;
    if (idx < N3 * DIM) {
        int k = idx % DIM, n = idx / DIM;
        wqkvt[idx] = (bf16_t)wqkv[(size_t)k * N3 + n];
    } else {
        int j = idx - N3 * DIM;
        if (j < DIM * DIM) {
            int k = j % DIM, n = j / DIM;
            woutt[j] = (bf16_t)wout[(size_t)k * DIM + n];
        }
    }
}

// ---------------- prep: bias+shift-mask tables  tbl[4][64][64] f32 ----------------
__global__ __launch_bounds__(256) void prep_tbl_kernel(const float* __restrict__ pe,
                                                       float* __restrict__ tbl) {
    int idx = blockIdx.x * 256 + threadIdx.x;     // 4*64*64 = 16384
    if (idx >= 4 * 64 * 64) return;
    int v = idx >> 12, rem = idx & 4095, ti = rem >> 6, tj = rem & 63;
    float val = -1e9f;
    if (ti < NTOK && tj < NTOK) {
        int yi = ti / 7, xi = ti % 7, yj = tj / 7, xj = tj % 7;
        val = pe[(yj - yi + 6) * 13 + (xj - xi + 6)];
        bool mr = (v & 2) && ((yi >= 4) != (yj >= 4));
        bool mc = (v & 1) && ((xi >= 4) != (xj >= 4));
        if (mr || mc) val = -1e9f;
    }
    tbl[idx] = val;
}

// ---------------- K1: fused QKV-projection + windowed attention (v2) ----------------
// block = (head, window, batch), 4 waves.
// W-tile (96 rows x 192) staged in LDS via global_load_lds + chunk-XOR swizzle.
// VT/P alias the W region (dead after phase 1). 47104 B LDS -> 3 blocks/CU.
__global__ __launch_bounds__(256) void fused_attn_kernel2(const bf16_t* __restrict__ xb,
                                                          const bf16_t* __restrict__ wt,
                                                          const float* __restrict__ tbl,
                                                          bf16_t* __restrict__ att) {
    const int h = blockIdx.x, win = blockIdx.y, bb = blockIdx.z;
    const int wh = win >> 3, ww = win & 7;
    const int mt = threadIdx.x >> 6;             // wave id
    const int lane = threadIdx.x & 63;
    const int lo = lane & 15, hi = lane >> 4;

    __shared__ alignas(16) bf16_t WL[96 * DIM];  // 36864 B, swizzled rows
    __shared__ alignas(16) bf16_t Qs[64 * 40];   // [tok][ch], stride 40 (80 B)
    __shared__ alignas(16) bf16_t Ks[64 * 40];
    bf16_t* VTs = WL;                            // alias: 32*72 elems (4608 B)
    bf16_t* P   = WL + 32 * 72;                  // alias: 64*72 elems (9216 B)

    // ---- stage W: rows (s*192 + h*32 + 0..31), s=0..2 -> LDS rows lr=s*32+r ----
    // chunk = 16 B; 24 chunks/row; swizzle: LDS chunk c holds global chunk c^((c/24)&7)
#pragma unroll
    for (int i = 0; i < 9; i++) {                // 9*256 = 2304 chunks
        int cbase = i * 256 + mt * 64;           // wave-uniform LDS chunk base
        int cid = cbase + lane;
        int seg = cid / 768;                     // wave never straddles a segment
        int c0 = cid - seg * 768;
        int g0 = c0 ^ ((c0 / 24) & 7);
        gld_lds16(wt + (size_t)(seg * DIM + h * HD) * DIM + g0 * 8,
                  WL + (size_t)cbase * 8);
    }

    // ---- A fragments: own 16 tokens from xb (6 x b128, issued before barrier) ----
    bf16x8 a[6];
    {
        int t = mt * 16 + lo;
        if (t >= NTOK) t = 0;                    // padded rows alias token 0
        int y = wh * WS7 + t / 7, xcol = ww * WS7 + t % 7;
        const bf16_t* ar = xb + ((size_t)(bb * HW + y) * HW + xcol) * DIM + hi * 8;
#pragma unroll
        for (int ks = 0; ks < 6; ks++)
            a[ks] = *reinterpret_cast<const bf16x8*>(ar + ks * 32);
    }

    __syncthreads();                             // W staged (vmcnt drained)

    // ---- phase 1: q,k,v projection; B-frags from swizzled LDS ----
    f32x4 acc6[3][2];
#pragma unroll
    for (int s = 0; s < 3; s++)
#pragma unroll
        for (int nt = 0; nt < 2; nt++) acc6[s][nt] = (f32x4){0.f, 0.f, 0.f, 0.f};

#pragma unroll
    for (int s = 0; s < 3; s++)
#pragma unroll
        for (int nt = 0; nt < 2; nt++) {
            int lr = s * 32 + nt * 16 + lo;
            const char* rowp = (const char*)WL + lr * 384;
            int rx = (lr & 7) << 4;
#pragma unroll
            for (int ks = 0; ks < 6; ks++) {
                bf16x8 bf = *reinterpret_cast<const bf16x8*>(rowp + ((ks * 64 + hi * 16) ^ rx));
                acc6[s][nt] = MFMA(a[ks], bf, acc6[s][nt]);
            }
        }

    __syncthreads();                             // all W reads done (VT/P alias W)

    // ---- phase 2: stage Q (prescaled), K token-major; V transposed ----
    const float qs = 0.17677669529663687f;       // 1/sqrt(32)
#pragma unroll
    for (int nt = 0; nt < 2; nt++)
#pragma unroll
        for (int r = 0; r < 4; r++) {
            int tok = mt * 16 + hi * 4 + r;
            Qs[tok * 40 + nt * 16 + lo] = (bf16_t)(acc6[0][nt][r] * qs);
            Ks[tok * 40 + nt * 16 + lo] = (bf16_t)acc6[1][nt][r];
            VTs[(nt * 16 + lo) * 72 + tok] = (bf16_t)acc6[2][nt][r];
        }
    __syncthreads();                             // Q/K/VT visible to all waves

    // ---- phase 3a: S = Q K^T  (one MFMA per 16x16 tile, K=32) ----
    const f32x4 zero4 = {0.f, 0.f, 0.f, 0.f};
    bf16x8 qa = *reinterpret_cast<const bf16x8*>(&Qs[(mt * 16 + lo) * 40 + hi * 8]);
    f32x4 s4[4];
#pragma unroll
    for (int ct = 0; ct < 4; ct++) {
        bf16x8 kb = *reinterpret_cast<const bf16x8*>(&Ks[(ct * 16 + lo) * 40 + hi * 8]);
        s4[ct] = MFMA(qa, kb, zero4);
    }

    // ---- phase 3b: softmax with bias+mask table ----
    const int variant = ((wh == 7) ? 2 : 0) | ((ww == 7) ? 1 : 0);
    const float* tbase = tbl + ((size_t)variant << 12);
    float rinv[4];
#pragma unroll
    for (int r = 0; r < 4; r++) {
        int ti = mt * 16 + hi * 4 + r;
        const float* trow = tbase + ti * 64 + lo;
        float vals[4];
        float mx = -3e38f;
#pragma unroll
        for (int ct = 0; ct < 4; ct++) {
            float v = s4[ct][r] + trow[ct * 16];
            vals[ct] = v;
            mx = fmaxf(mx, v);
        }
#pragma unroll
        for (int off = 1; off < 16; off <<= 1) mx = fmaxf(mx, __shfl_xor(mx, off));
        float sum = 0.f;
#pragma unroll
        for (int ct = 0; ct < 4; ct++) {
            float p = __expf(vals[ct] - mx);
            sum += p;
            P[ti * 72 + ct * 16 + lo] = (bf16_t)p;
        }
#pragma unroll
        for (int off = 1; off < 16; off <<= 1) sum += __shfl_xor(sum, off);
        rinv[r] = 1.f / sum;
    }

    // ---- phase 3c: O = P V  (P rows wave-local; VTs barrier'd above) ----
    f32x4 o[2] = {zero4, zero4};
#pragma unroll
    for (int ks = 0; ks < 2; ks++) {
        bf16x8 pa = *reinterpret_cast<const bf16x8*>(&P[(mt * 16 + lo) * 72 + ks * 32 + hi * 8]);
#pragma unroll
        for (int c2 = 0; c2 < 2; c2++) {
            bf16x8 vb = *reinterpret_cast<const bf16x8*>(&VTs[(c2 * 16 + lo) * 72 + ks * 32 + hi * 8]);
            o[c2] = MFMA(pa, vb, o[c2]);
        }
    }

#pragma unroll
    for (int r = 0; r < 4; r++) {
        int ti = mt * 16 + hi * 4 + r;
        if (ti < NTOK) {
            int y = wh * WS7 + ti / 7, xcol = ww * WS7 + ti % 7;
            size_t aoff = ((size_t)(bb * HW + y) * HW + xcol) * DIM + h * HD;
#pragma unroll
            for (int c2 = 0; c2 < 2; c2++)
                att[aoff + c2 * 16 + lo] = (bf16_t)(o[c2][r] * rinv[r]);
        }
    }
}

// ---------------- K3: out GEMM + bias + roll(+3,+3) ----------------
__global__ __launch_bounds__(256) void out_gemm2(const bf16_t* __restrict__ att,
                                                 const bf16_t* __restrict__ wt,
                                                 const float* __restrict__ bias,
                                                 float* __restrict__ out) {
    __shared__ alignas(16) bf16_t bsh[64 * DIM];
    const int mblk = blockIdx.x, nblk = blockIdx.y;
    const int wave = threadIdx.x >> 6, lane = threadIdx.x & 63;
    const int lo = lane & 15, hi = lane >> 4;

    const bf16_t* bt = wt + (size_t)nblk * 64 * DIM;
#pragma unroll
    for (int i = 0; i < 6; i++) {
        int s = wave * 384 + i * 64 + lane;
        int g = s ^ ((s / 24) & 7);
        gld_lds16(bt + g * 8, bsh + (wave * 384 + i * 64) * 8);
    }

    bf16x8 a[2][6];
    const bf16_t* ab = att + ((size_t)mblk * 128 + wave * 32 + lo) * DIM + hi * 8;
#pragma unroll
    for (int mt = 0; mt < 2; mt++)
#pragma unroll
        for (int ks = 0; ks < 6; ks++)
            a[mt][ks] = *reinterpret_cast<const bf16x8*>(ab + mt * 16 * DIM + ks * 32);

    f32x4 acc[2][4];
#pragma unroll
    for (int mt = 0; mt < 2; mt++)
#pragma unroll
        for (int ct = 0; ct < 4; ct++) acc[mt][ct] = (f32x4){0.f, 0.f, 0.f, 0.f};

    __syncthreads();

#pragma unroll
    for (int ks = 0; ks < 6; ks++)
#pragma unroll
        for (int ct = 0; ct < 4; ct++) {
            int r = ct * 16 + lo;
            int off = (ks * 64 + hi * 16) ^ ((r & 7) << 4);
            bf16x8 b = *reinterpret_cast<const bf16x8*>((const char*)bsh + r * 384 + off);
            acc[0][ct] = MFMA(a[0][ks], b, acc[0][ct]);
            acc[1][ct] = MFMA(a[1][ks], b, acc[1][ct]);
        }

    const int rb = mblk * 128 + wave * 32;
#pragma unroll
    for (int mt = 0; mt < 2; mt++)
#pragma unroll
        for (int r = 0; r < 4; r++) {
            int m = rb + mt * 16 + hi * 4 + r;
            int bb = m / (HW * HW);
            int rem = m - bb * HW * HW;
            int ya = rem / HW, xa = rem - ya * HW;
            int yo = ya + 3; if (yo >= HW) yo -= HW;
            int xo = xa + 3; if (xo >= HW) xo -= HW;
            size_t ob = ((size_t)(bb * HW + yo) * HW + xo) * DIM + nblk * 64;
#pragma unroll
            for (int ct = 0; ct < 4; ct++)
                out[ob + ct * 16 + lo] = acc[mt][ct][r] + bias[nblk * 64 + ct * 16 + lo];
        }
}

extern "C" void kernel_launch(void* const* d_in, const int* in_sizes, int n_in,
                              void* d_out, int out_size, void* d_ws, size_t ws_size,
                              hipStream_t stream) {
    const float* x    = (const float*)d_in[0];
    const float* wqkv = (const float*)d_in[1];
    const float* pe   = (const float*)d_in[2];
    const float* wout = (const float*)d_in[3];
    const float* bout = (const float*)d_in[4];
    float* out = (float*)d_out;

    char* ws = (char*)d_ws;
    const size_t XB_BYTES  = (size_t)NB * HW * HW * DIM * 2;   // 19,267,584
    const size_t ATT_BYTES = XB_BYTES;
    const size_t WQ_BYTES  = (size_t)N3 * DIM * 2;
    const size_t WO_BYTES  = (size_t)DIM * DIM * 2;
    bf16_t* xb    = (bf16_t*)ws;
    bf16_t* att   = (bf16_t*)(ws + XB_BYTES);
    bf16_t* wqkvt = (bf16_t*)(ws + XB_BYTES + ATT_BYTES);
    bf16_t* woutt = (bf16_t*)(ws + XB_BYTES + ATT_BYTES + WQ_BYTES);
    float*  tbl   = (float*)(ws + XB_BYTES + ATT_BYTES + WQ_BYTES + WO_BYTES);

    prep_x_kernel<<<(NB * HW * HW * (DIM / 8) + 255) / 256, 256, 0, stream>>>(x, xb);
    prep_w_kernel<<<(N3 * DIM + DIM * DIM + 255) / 256, 256, 0, stream>>>(wqkv, wout, wqkvt, woutt);
    prep_tbl_kernel<<<64, 256, 0, stream>>>(pe, tbl);
    fused_attn_kernel2<<<dim3(HEADS, 64, NB), 256, 0, stream>>>(xb, wqkvt, tbl, att);
    out_gemm2<<<dim3(392, 3), 256, 0, stream>>>(att, woutt, bout, out);
}